// Round 7
// baseline (119.128 us; speedup 1.0000x reference)
//
#include <hip/hip_runtime.h>

typedef unsigned short u16;
typedef __attribute__((ext_vector_type(8))) short short8;
typedef __attribute__((ext_vector_type(4))) float f32x4;

#define B_  64
#define IC  64
#define OC  64
#define NG  2048
#define MD  512

__device__ inline u16 f2b(float f) {
  unsigned u = __float_as_uint(f);
  unsigned r = (u + 0x7FFFu + ((u >> 16) & 1u)) >> 16;
  return (u16)r;
}

__device__ __forceinline__ float cosk(int k, int n) {
  int r = (k * n) % (2 * (NG - 1));
  return __cosf((float)r * (3.14159265358979323846f / (NG - 1)));
}

// async global->LDS, 16 B per lane. LDS dest is wave-uniform base + lane*16.
__device__ __forceinline__ void gld_lds16(const u16* g, const u16* l) {
  __builtin_amdgcn_global_load_lds(
      (__attribute__((address_space(1))) void*)(uintptr_t)(g),
      (__attribute__((address_space(3))) void*)(unsigned)(uintptr_t)(l),
      16, 0, 0);
}

// ================= fused prologue =================
// DCT-I reflection symmetry: cos(pi*k*(2047-n)/2047) = (-1)^k cos(pi*k*n/2047).
// grid: [0,4096) fold x -> e,o | [4096,4608) w->wT2 | [4608,6656) M1'' (perm rows)
//       [6656,8704) M3e/M3o
__global__ __launch_bounds__(256) void prep(
    const float* __restrict__ x, const float* __restrict__ w,
    u16* __restrict__ e, u16* __restrict__ o, u16* __restrict__ wT2,
    u16* __restrict__ M1p, u16* __restrict__ M3e, u16* __restrict__ M3o) {
  __shared__ float S[64][65];
  const int id = blockIdx.x;
  const int t = threadIdx.x;
  if (id < 4096) {                      // ---- e/o fold: one x row per block ----
    const float* xr = x + (size_t)id * NG;
    float4 f = *(const float4*)(xr + 4 * t);
    float4 b = *(const float4*)(xr + (2044 - 4 * t));
    ushort4 ev, ov;
    ev.x = f2b(f.x + b.w); ov.x = f2b(f.x - b.w);
    ev.y = f2b(f.y + b.z); ov.y = f2b(f.y - b.z);
    ev.z = f2b(f.z + b.y); ov.z = f2b(f.z - b.y);
    ev.w = f2b(f.w + b.x); ov.w = f2b(f.w - b.x);
    *(ushort4*)(e + (size_t)id * 1024 + 4 * t) = ev;
    *(ushort4*)(o + (size_t)id * 1024 + 4 * t) = ov;
  } else if (id < 4608) {               // ---- wT2[k][o*64+i] = w[i][o][k] ----
    int wb = id - 4096;
    int oo = wb & 63, kb = wb >> 6;
    int r0 = t >> 6, c = t & 63;
#pragma unroll
    for (int j = 0; j < 16; ++j) {
      int i = r0 + j * 4;
      S[i][c] = w[(size_t)(i * 64 + oo) * MD + kb * 64 + c];
    }
    __syncthreads();
#pragma unroll
    for (int j = 0; j < 16; ++j) {
      int kk = r0 + j * 4;
      wT2[(size_t)(kb * 64 + kk) * 4096 + oo * 64 + c] = f2b(S[c][kk]);
    }
  } else if (id < 6656) {               // ---- M1''[r][n], r<256: k=2r else k=2(r-256)+1 ----
    int idx = (id - 4608) * 256 + t;    // 512K
    int r = idx >> 10, n = idx & 1023;
    int k = (r < 256) ? 2 * r : 2 * (r - 256) + 1;
    float v = cosk(k, n) * ((n == 0) ? 1.0f : 2.0f);
    M1p[idx] = f2b(v);
  } else {                              // ---- M3e/M3o [1024][256] ----
    int idx = (id - 6656) * 256 + t;    // 512K
    int half = idx >> 18;
    int rem = idx & 262143;
    int n = rem >> 8, kp = rem & 255;
    if (half == 0) {
      float v = cosk(2 * kp, n) * ((kp == 0) ? 1.0f : 2.0f);
      M3e[rem] = f2b(v);
    } else {
      float v = cosk(2 * kp + 1, n) * 2.0f;
      M3o[rem] = f2b(v);
    }
  }
}

// ================= G1: one-wave 64x64 tile, K=1024, dbuf async staging ========
// xcT[m][n] = sum_k M1p[m][k] * {e|o}[n][k]   (m: permuted mode rows; n: b*64+i)
// 64 threads = 1 wave; MI=NI=4 (wave covers whole 64x64 tile) -> each LDS row
// read exactly once per K-step: 16 KB reads per 16 KB staged (re-read factor 1).
// XOR swizzle: physical chunk = logical chunk ^ (row&7).
__global__ __launch_bounds__(64) void gemm_g1(
    const u16* __restrict__ A,    // [512][1024] bf16 (M1p)
    const u16* __restrict__ Bt0,  // e [4096][1024]
    const u16* __restrict__ Bt1,  // o [4096][1024]
    u16* __restrict__ C) {        // xcT [512][4096] bf16
  constexpr int K = 1024;
  constexpr int BK = 64;
  constexpr int BUF = 128 * BK;   // 16 KB per buffer
  __shared__ u16 S[2 * BUF];

  const int lane = threadIdx.x;
  const long bm = (long)blockIdx.y * 64;
  const long bn = (long)blockIdx.x * 64;
  const u16* Bt = ((int)blockIdx.y < 4) ? Bt0 : Bt1;

  const int lrow = lane & 15;
  const int lhi  = lane >> 4;
  const int scc = (((lane & 7) ^ (lane >> 3)) * 8);

  // staging: 16 issues of 8 rows (1 KB); rows 0-63 = A-tile, 64-127 = B-tile
  const u16* Ab = A  + (bm + (lane >> 3)) * (long)K + scc;
  const u16* Bb = Bt + (bn + (lane >> 3)) * (long)K + scc;

  f32x4 acc[4][4] = {};

  // prologue: stage k0=0 into buffer 0
#pragma unroll
  for (int ii = 0; ii < 8; ++ii) {
    gld_lds16(Ab + (long)ii * 8 * K, &S[ii * 8 * BK]);
    gld_lds16(Bb + (long)ii * 8 * K, &S[(64 + ii * 8) * BK]);
  }

  int p = 0;
  for (int k0 = 0; k0 < K; k0 += BK) {
    __syncthreads();   // single-wave: drains vmcnt for buffer p

    if (k0 + BK < K) {
      const unsigned bo = (unsigned)((1 - p) * BUF);
#pragma unroll
      for (int ii = 0; ii < 8; ++ii) {
        gld_lds16(Ab + (long)ii * 8 * K + k0 + BK, &S[bo + ii * 8 * BK]);
        gld_lds16(Bb + (long)ii * 8 * K + k0 + BK, &S[bo + (64 + ii * 8) * BK]);
      }
    }

    const u16* Sp = &S[p * BUF];
#pragma unroll
    for (int kk8 = 0; kk8 < 8; kk8 += 4) {
      const int pchA = (kk8 + lhi) ^ (lrow & 7);
      short8 af[4], bfr[4];
#pragma unroll
      for (int i = 0; i < 4; ++i)
        af[i] = *(const short8*)&Sp[(i * 16 + lrow) * BK + pchA * 8];
#pragma unroll
      for (int j = 0; j < 4; ++j)
        bfr[j] = *(const short8*)&Sp[(64 + j * 16 + lrow) * BK + pchA * 8];
#pragma unroll
      for (int i = 0; i < 4; ++i)
#pragma unroll
        for (int j = 0; j < 4; ++j)
          acc[i][j] = __builtin_amdgcn_mfma_f32_16x16x32_bf16(af[i], bfr[j], acc[i][j], 0, 0, 0);
    }
    p ^= 1;
  }

  const int crow = lhi * 4;
  const int ccol = lane & 15;
#pragma unroll
  for (int i = 0; i < 4; ++i)
#pragma unroll
    for (int j = 0; j < 4; ++j) {
      long gm = bm + i * 16 + crow;
      long gn = bn + j * 16 + ccol;
      u16* cp = C + gm * (long)4096 + gn;
#pragma unroll
      for (int r = 0; r < 4; ++r)
        cp[(long)r * 4096] = f2b(acc[i][j][r]);
    }
}

// ================= per-mode 64x64x64 mix via MFMA =================
// omT[k][b*64+o] = sum_i xcT[rk(k)][b*64+i] * wT2[k][o*64+i]
// xcT rows are permuted: row r<256 holds even k=2r, else odd.
__global__ __launch_bounds__(256, 4) void mode_mix_mfma(
    const u16* __restrict__ xcT,   // [512][4096] bf16 (permuted rows)
    const u16* __restrict__ wT2,   // [512][4096] bf16 (o*64+i order)
    u16* __restrict__ omT) {       // [512][4096] bf16 (k order)
  constexpr int PK = 72;
  __shared__ u16 S[128 * PK];
  const int k = blockIdx.x;
  const int rk = (k & 1) ? 256 + (k >> 1) : (k >> 1);
  const int t = threadIdx.x;

#pragma unroll
  for (int c = 0; c < 4; ++c) {
    int ch = t + c * 256;
    int half = ch >> 9, cc = ch & 511;
    int row = cc >> 3, col8 = cc & 7;
    const u16* src = half ? (wT2 + (size_t)k * 4096)
                          : (xcT + (size_t)rk * 4096);
    uint4 v = *(const uint4*)(src + row * 64 + col8 * 8);
    *(uint4*)&S[(half * 64 + row) * PK + col8 * 8] = v;
  }
  __syncthreads();

  const int lane = t & 63;
  const int wave = t >> 6;
  const int wm = (wave >> 1) * 32;
  const int wn = (wave & 1) * 32;
  const int lrow = lane & 15;
  const int lhi  = lane >> 4;

  f32x4 acc[2][2] = {};
#pragma unroll
  for (int kk8 = 0; kk8 < 8; kk8 += 4) {
    short8 af[2], bfr[2];
#pragma unroll
    for (int i = 0; i < 2; ++i)
      af[i] = *(const short8*)&S[(wm + i * 16 + lrow) * PK + (kk8 + lhi) * 8];
#pragma unroll
    for (int j = 0; j < 2; ++j)
      bfr[j] = *(const short8*)&S[(64 + wn + j * 16 + lrow) * PK + (kk8 + lhi) * 8];
#pragma unroll
    for (int i = 0; i < 2; ++i)
#pragma unroll
      for (int j = 0; j < 2; ++j)
        acc[i][j] = __builtin_amdgcn_mfma_f32_16x16x32_bf16(af[i], bfr[j], acc[i][j], 0, 0, 0);
  }

  const int crow = (lane >> 4) * 4;
  const int ccol = lane & 15;
#pragma unroll
  for (int i = 0; i < 2; ++i)
#pragma unroll
    for (int j = 0; j < 2; ++j) {
      int b = wm + i * 16 + crow;
      int oo = wn + j * 16 + ccol;
#pragma unroll
      for (int r = 0; r < 4; ++r)
        omT[(size_t)k * 4096 + (b + r) * 64 + oo] = f2b(acc[i][j][r]);
    }
}

// ====== bf16 transpose with even/odd column split: omT [512][4096] -> om' ======
// om'[bo][k'] : k'<256 holds k=2k' (even), k'>=256 holds k=2(k'-256)+1 (odd)
__global__ __launch_bounds__(256) void transpose_om(const u16* __restrict__ omT,
                                                    u16* __restrict__ omp) {
  __shared__ u16 S[64][65];
  const int bb = blockIdx.x;
  const int kb = blockIdx.y;
  const int t = threadIdx.x;
  const int r0 = t >> 6;
  const int c  = t & 63;
#pragma unroll
  for (int j = 0; j < 16; ++j) {
    int kr = r0 + j * 4;
    S[kr][c] = omT[(size_t)(kb * 64 + kr) * 4096 + bb * 64 + c];
  }
  __syncthreads();
  const int col = ((c & 1) ? 256 : 0) + kb * 32 + (c >> 1);
#pragma unroll
  for (int j = 0; j < 16; ++j) {
    int br = r0 + j * 4;
    omp[(size_t)(bb * 64 + br) * MD + col] = S[c][br];
  }
}

// ================= G3: dual half-K GEMM + in-wave butterfly =================
// E[bo][n] = sum_{k'<256} om'[bo][k']   * M3e[n][k']
// O[bo][n] = sum_{k'<256} om'[bo][256+k']*M3o[n][k']
// out[bo][n] = E+O ; out[bo][2047-n] = E-O   (n < 1024)
// Block: 128 bo x 64 n. 4 waves stacked (32 bo each, MI=2, NI=4). BK=64, 4 steps.
// LDS rows: [0,128) A_e | [128,256) A_o | [256,320) Be | [320,384) Bo; 48 KB.
__global__ __launch_bounds__(256, 2) void gemm_g3(
    const u16* __restrict__ omp,   // [4096][512] bf16 (even|odd halves)
    const u16* __restrict__ M3e,   // [1024][256] bf16
    const u16* __restrict__ M3o,   // [1024][256] bf16
    float* __restrict__ out) {     // [4096][2048] fp32
  constexpr int BK = 64;
  constexpr int ROWS = 384;
  constexpr int CH = ROWS / 4;     // 96 rows per wave
  constexpr int NISSUE = CH / 8;   // 12
  __shared__ u16 S[ROWS * BK];

  const int tid  = threadIdx.x;
  const int lane = tid & 63;
  const int wave = tid >> 6;
  const long bm = (long)blockIdx.y * 128;
  const int n0 = blockIdx.x * 64;

  const int lrow = lane & 15;
  const int lhi  = lane >> 4;
  const int scc = (((lane & 7) ^ (lane >> 3)) * 8);
  const int r0 = wave * CH;

  const u16* gsrc[NISSUE];
  unsigned lofs[NISSUE];
#pragma unroll
  for (int ii = 0; ii < NISSUE; ++ii) {
    int rr = r0 + ii * 8 + (lane >> 3);
    const u16* p;
    if (rr < 128)       p = omp + (bm + rr) * (long)512 + scc;
    else if (rr < 256)  p = omp + (bm + rr - 128) * (long)512 + 256 + scc;
    else if (rr < 320)  p = M3e + (n0 + rr - 256) * (long)256 + scc;
    else                p = M3o + (n0 + rr - 320) * (long)256 + scc;
    gsrc[ii] = p;
    lofs[ii] = (unsigned)((r0 + ii * 8) * BK);
  }

  f32x4 accE[2][4] = {};
  f32x4 accO[2][4] = {};

  for (int k0 = 0; k0 < 256; k0 += BK) {
#pragma unroll
    for (int ii = 0; ii < NISSUE; ++ii)
      gld_lds16(gsrc[ii] + k0, &S[lofs[ii]]);
    __syncthreads();

#pragma unroll
    for (int kk8 = 0; kk8 < 8; kk8 += 4) {
      int pch = ((kk8 + lhi) ^ (lane & 7));
      short8 aE[2], aO[2], bE[4], bO[4];
#pragma unroll
      for (int i = 0; i < 2; ++i) {
        aE[i] = *(const short8*)&S[(wave * 32 + i * 16 + lrow) * BK + pch * 8];
        aO[i] = *(const short8*)&S[(128 + wave * 32 + i * 16 + lrow) * BK + pch * 8];
      }
#pragma unroll
      for (int j = 0; j < 4; ++j) {
        bE[j] = *(const short8*)&S[(256 + j * 16 + lrow) * BK + pch * 8];
        bO[j] = *(const short8*)&S[(320 + j * 16 + lrow) * BK + pch * 8];
      }
#pragma unroll
      for (int i = 0; i < 2; ++i)
#pragma unroll
        for (int j = 0; j < 4; ++j) {
          accE[i][j] = __builtin_amdgcn_mfma_f32_16x16x32_bf16(aE[i], bE[j], accE[i][j], 0, 0, 0);
          accO[i][j] = __builtin_amdgcn_mfma_f32_16x16x32_bf16(aO[i], bO[j], accO[i][j], 0, 0, 0);
        }
    }
    __syncthreads();
  }

  const int crow = (lane >> 4) * 4;
  const int ccol = lane & 15;
#pragma unroll
  for (int i = 0; i < 2; ++i)
#pragma unroll
    for (int j = 0; j < 4; ++j) {
      long bo = bm + wave * 32 + i * 16 + crow;
      int n = n0 + j * 16 + ccol;
      float* op = out + bo * (long)NG;
#pragma unroll
      for (int r = 0; r < 4; ++r) {
        float E = accE[i][j][r], O = accO[i][j][r];
        op[(long)r * NG + n] = E + O;
        op[(long)r * NG + (NG - 1 - n)] = E - O;
      }
    }
}

extern "C" void kernel_launch(void* const* d_in, const int* in_sizes, int n_in,
                              void* d_out, int out_size, void* d_ws, size_t ws_size,
                              hipStream_t stream) {
  const float* x = (const float*)d_in[0];   // [B_][IC][NG]
  const float* w = (const float*)d_in[1];   // [IC][OC][MD]
  float* out = (float*)d_out;               // [B_][OC][NG]

  // ws layout (36 MB):
  //  [0,8M): e | [8,16M): o | [16,17M): M1'' | [17,17.5M): M3e | [17.5,18M): M3o
  //  [20,24M): xcT bf16 (permuted rows) | [24,28M): wT2 | [28,32M): omT | [32,36M): om'
  char* ws = (char*)d_ws;
  u16* e    = (u16*)ws;
  u16* o    = (u16*)(ws + (size_t)8 * 1024 * 1024);
  u16* M1p  = (u16*)(ws + (size_t)16 * 1024 * 1024);
  u16* M3e  = (u16*)(ws + (size_t)17 * 1024 * 1024);
  u16* M3o  = (u16*)(ws + (size_t)17 * 1024 * 1024 + 512 * 1024);
  u16* xcT  = (u16*)(ws + (size_t)20 * 1024 * 1024);
  u16* wT2  = (u16*)(ws + (size_t)24 * 1024 * 1024);
  u16* omT  = (u16*)(ws + (size_t)28 * 1024 * 1024);
  u16* omp  = (u16*)(ws + (size_t)32 * 1024 * 1024);

  // fused prologue: e/o fold + w-transpose + M1'' + M3e/M3o
  prep<<<8704, 256, 0, stream>>>(x, w, e, o, wT2, M1p, M3e, M3o);

  // G1: xcT[512][4096] = M1''[512][1024] * {e|o}[4096][1024]^T  (K=1024)
  // one wave per 64x64 tile; rows r<256 (even k) pair with e -> blockIdx.y<4
  gemm_g1<<<dim3((B_ * IC) / 64, 512 / 64), 64, 0, stream>>>(M1p, e, o, xcT);

  // per-mode MFMA mix: omT[512][4096]
  mode_mix_mfma<<<MD, 256, 0, stream>>>(xcT, wT2, omT);

  // transpose + even/odd split to om'[4096][512]
  transpose_om<<<dim3((B_ * OC) / 64, MD / 64), 256, 0, stream>>>(omT, omp);

  // G3: dual half-K GEMM + butterfly -> out[4096][2048]
  gemm_g3<<<dim3(1024 / 64, (B_ * OC) / 128), 256, 0, stream>>>(omp, M3e, M3o, out);
}